// Round 1
// baseline (281.564 us; speedup 1.0000x reference)
//
#include <hip/hip_runtime.h>
#include <hip/hip_bf16.h>

// Problem constants (fixed by reference): B=1024, K=256, D=1024, P=768
#define BM 64
#define BN 64
#define BK 16

// C[M,N] = scale * A[M,Kd] @ (TRANSB ? Bm[N,Kd]^T : Bm[Kd,N]) (+ addend[M,N])
// Requires: M%64==0, N%64==0, Kd%16==0. 256 threads/block.
template<bool TRANSB, bool HASADD>
__global__ __launch_bounds__(256)
void gemm_tile(const float* __restrict__ A, const float* __restrict__ Bm,
               const float* __restrict__ addend, float* __restrict__ C,
               int M, int N, int Kd, float scale)
{
    __shared__ __align__(16) float As[BK][BM];   // As[k][m]
    __shared__ __align__(16) float Bs[BK][BN];   // Bs[k][n]
    const int t  = threadIdx.x;
    const int tx = t & 15;   // n-direction (4 cols each)
    const int ty = t >> 4;   // m-direction (4 rows each)
    const int m0 = blockIdx.y * BM;
    const int n0 = blockIdx.x * BN;

    float acc[4][4] = {};

    for (int k0 = 0; k0 < Kd; k0 += BK) {
        // ---- stage A tile: 64 rows x 16 k, one float4 per thread, transposed store
        {
            const int row = t >> 2;
            const int c   = (t & 3) << 2;
            const float4 av = *(const float4*)(A + (size_t)(m0 + row) * Kd + k0 + c);
            As[c + 0][row] = av.x; As[c + 1][row] = av.y;
            As[c + 2][row] = av.z; As[c + 3][row] = av.w;
        }
        // ---- stage B tile
        if (TRANSB) {
            // Bm is [N, Kd]; tile rows n0..n0+63, k-cols k0..k0+15
            const int n = t >> 2;
            const int c = (t & 3) << 2;
            const float4 bv = *(const float4*)(Bm + (size_t)(n0 + n) * Kd + k0 + c);
            Bs[c + 0][n] = bv.x; Bs[c + 1][n] = bv.y;
            Bs[c + 2][n] = bv.z; Bs[c + 3][n] = bv.w;
        } else {
            // Bm is [Kd, N]; tile rows k0..k0+15, cols n0..n0+63
            const int kk = t >> 4;
            const int c  = (t & 15) << 2;
            const float4 bv = *(const float4*)(Bm + (size_t)(k0 + kk) * N + n0 + c);
            *(float4*)&Bs[kk][c] = bv;   // row stride 256B -> 16B-aligned
        }
        __syncthreads();

        #pragma unroll
        for (int kk = 0; kk < BK; ++kk) {
            const float4 a = *(const float4*)&As[kk][ty << 2];
            const float4 b = *(const float4*)&Bs[kk][tx << 2];
            acc[0][0] += a.x * b.x; acc[0][1] += a.x * b.y; acc[0][2] += a.x * b.z; acc[0][3] += a.x * b.w;
            acc[1][0] += a.y * b.x; acc[1][1] += a.y * b.y; acc[1][2] += a.y * b.z; acc[1][3] += a.y * b.w;
            acc[2][0] += a.z * b.x; acc[2][1] += a.z * b.y; acc[2][2] += a.z * b.z; acc[2][3] += a.z * b.w;
            acc[3][0] += a.w * b.x; acc[3][1] += a.w * b.y; acc[3][2] += a.w * b.z; acc[3][3] += a.w * b.w;
        }
        __syncthreads();
    }

    // ---- epilogue
    #pragma unroll
    for (int i = 0; i < 4; ++i) {
        const size_t off = (size_t)(m0 + (ty << 2) + i) * N + n0 + (tx << 2);
        float4 r;
        r.x = acc[i][0] * scale; r.y = acc[i][1] * scale;
        r.z = acc[i][2] * scale; r.w = acc[i][3] * scale;
        if (HASADD) {
            const float4 ad = *(const float4*)(addend + off);
            r.x += ad.x; r.y += ad.y; r.z += ad.z; r.w += ad.w;
        }
        *(float4*)(C + off) = r;
    }
}

// cp[k,d] = conf[k,d] * prior[k]   (D == 1024, power of two)
__global__ __launch_bounds__(256)
void scale_rows_kernel(const float* __restrict__ conf, const float* __restrict__ prior,
                       float* __restrict__ cp)
{
    const int idx = blockIdx.x * 256 + threadIdx.x;
    const int k = idx >> 10;            // / 1024
    cp[idx] = conf[idx] * prior[k];
}

// in-place softmax over rows of length 256; one block (256 threads) per row
__global__ __launch_bounds__(256)
void softmax_rows_kernel(float* __restrict__ attn)
{
    __shared__ float red[256];
    const int b = blockIdx.x;
    const int t = threadIdx.x;
    const float v = attn[b * 256 + t];

    red[t] = v; __syncthreads();
    #pragma unroll
    for (int s = 128; s > 0; s >>= 1) {
        if (t < s) red[t] = fmaxf(red[t], red[t + s]);
        __syncthreads();
    }
    const float mx = red[0];
    __syncthreads();

    const float e = __expf(v - mx);
    red[t] = e; __syncthreads();
    #pragma unroll
    for (int s = 128; s > 0; s >>= 1) {
        if (t < s) red[t] += red[t + s];
        __syncthreads();
    }
    const float inv = 1.0f / red[0];
    attn[b * 256 + t] = e * inv;
}

extern "C" void kernel_launch(void* const* d_in, const int* in_sizes, int n_in,
                              void* d_out, int out_size, void* d_ws, size_t ws_size,
                              hipStream_t stream)
{
    const int Bn = 1024, Kc = 256, Dd = 1024, Pp = 768;

    const float* joint = (const float*)d_in[0];  // [B, D]
    const float* conf  = (const float*)d_in[1];  // [K, D]
    const float* prior = (const float*)d_in[2];  // [K]
    const float* Wq    = (const float*)d_in[3];  // [D, P]
    const float* Wk    = (const float*)d_in[4];  // [D, P]
    float* out = (float*)d_out;                  // [B, D]

    float* ws   = (float*)d_ws;
    float* q    = ws;               // B*P   = 786432
    float* km   = q    + Bn * Pp;   // K*P   = 196608
    float* attn = km   + Kc * Pp;   // B*K   = 262144
    float* cp   = attn + Bn * Kc;   // K*D   = 262144   (total ~5.75 MB)

    // cp = conf * prior
    scale_rows_kernel<<<(Kc * Dd) / 256, 256, 0, stream>>>(conf, prior, cp);

    // q = joint @ Wq   [1024,768]
    gemm_tile<false, false><<<dim3(Pp / BN, Bn / BM), 256, 0, stream>>>(
        joint, Wq, nullptr, q, Bn, Pp, Dd, 1.0f);

    // km = conf @ Wk   [256,768]
    gemm_tile<false, false><<<dim3(Pp / BN, Kc / BM), 256, 0, stream>>>(
        conf, Wk, nullptr, km, Kc, Pp, Dd, 1.0f);

    // scores = (q @ km^T) / 32   [1024,256]
    gemm_tile<true, false><<<dim3(Kc / BN, Bn / BM), 256, 0, stream>>>(
        q, km, nullptr, attn, Bn, Kc, Pp, 0.03125f);

    // softmax rows
    softmax_rows_kernel<<<Bn, 256, 0, stream>>>(attn);

    // out = joint + attn @ cp   [1024,1024]
    gemm_tile<false, true><<<dim3(Dd / BN, Bn / BM), 256, 0, stream>>>(
        attn, cp, joint, out, Bn, Dd, Kc, 1.0f);
}

// Round 2
// 130.982 us; speedup vs baseline: 2.1496x; 2.1496x over previous
//
#include <hip/hip_runtime.h>
#include <hip/hip_bf16.h>

// B=1024, K(conf)=256, D=1024, P=768. All GEMMs NT-form bf16 MFMA.

typedef __attribute__((ext_vector_type(8))) short short8;   // 8 bf16 = 4 VGPRs
typedef __attribute__((ext_vector_type(4))) float f32x4;    // MFMA accumulator

__device__ __forceinline__ ushort f2bf(float x) {
    union { float f; uint u; } c; c.f = x;
    const uint u = c.u;
    return (ushort)((u + 0x7FFFu + ((u >> 16) & 1u)) >> 16);  // RNE
}

// ---------------------------------------------------------------------------
// prep: one launch builds all bf16 NT operands.
//   blocks [0,1024)    : Jb    = bf16(J)              flat, 1024 elems/block
//   blocks [1024,1280) : confb = bf16(conf)           flat
//   blocks [1280,2048) : WqT[p][d] = bf16(Wq[d][p])   32x32 tiled transpose
//   blocks [2048,2816) : WkT[p][d] = bf16(Wk[d][p])
//   blocks [2816,3072) : cpT[d][k] = bf16(conf[k][d]*prior[k])
// ---------------------------------------------------------------------------
__global__ __launch_bounds__(256)
void prep_kernel(const float* __restrict__ J, const float* __restrict__ conf,
                 const float* __restrict__ prior, const float* __restrict__ Wq,
                 const float* __restrict__ Wk,
                 ushort* __restrict__ Jb, ushort* __restrict__ confb,
                 ushort* __restrict__ WqT, ushort* __restrict__ WkT,
                 ushort* __restrict__ cpT)
{
    const int t = threadIdx.x;
    int b = blockIdx.x;

    if (b < 1280) {  // flat convert
        const float* src; ushort* dst; int base;
        if (b < 1024) { src = J;    dst = Jb;    base = b * 1024; }
        else          { src = conf; dst = confb; base = (b - 1024) * 1024; }
        const float4 v = *(const float4*)(src + base + t * 4);
        ushort4 o;
        o.x = f2bf(v.x); o.y = f2bf(v.y); o.z = f2bf(v.z); o.w = f2bf(v.w);
        *(ushort4*)(dst + base + t * 4) = o;
        return;
    }

    __shared__ float tile[32][33];
    const float* src; ushort* dst; int R, C, tpr; bool usePrior;
    if (b < 2048)      { b -= 1280; src = Wq;   dst = WqT; R = 1024; C = 768;  tpr = 24; usePrior = false; }
    else if (b < 2816) { b -= 2048; src = Wk;   dst = WkT; R = 1024; C = 768;  tpr = 24; usePrior = false; }
    else               { b -= 2816; src = conf; dst = cpT; R = 256;  C = 1024; tpr = 32; usePrior = true;  }
    const int rt = b / tpr, ct = b % tpr;

    {   // load 32x32 tile (coalesced), scaled by prior if needed
        const int row = t >> 3, c4 = (t & 7) << 2;
        const float4 v = *(const float4*)(src + (size_t)(rt * 32 + row) * C + ct * 32 + c4);
        const float p = usePrior ? prior[rt * 32 + row] : 1.0f;
        tile[row][c4 + 0] = v.x * p; tile[row][c4 + 1] = v.y * p;
        tile[row][c4 + 2] = v.z * p; tile[row][c4 + 3] = v.w * p;
    }
    __syncthreads();
    {   // store transposed (coalesced in output)
        const int orow = t >> 3, oc4 = (t & 7) << 2;
        ushort4 o;
        o.x = f2bf(tile[oc4 + 0][orow]); o.y = f2bf(tile[oc4 + 1][orow]);
        o.z = f2bf(tile[oc4 + 2][orow]); o.w = f2bf(tile[oc4 + 3][orow]);
        *(ushort4*)(dst + (size_t)(ct * 32 + orow) * R + rt * 32 + oc4) = o;
    }
}

// ---------------------------------------------------------------------------
// NT MFMA GEMM: C[M,N] = scale * A[M,K] @ B[N,K]^T (+ addend[M,N])
// A,B bf16 (ushort bits), row stride K. 128x128 block tile, 4 waves of 64x64,
// BK=32 -> one 16x16x32 MFMA consumes a full K-step.
// Requires M%128==0, N%128==0, K%32==0.
// ---------------------------------------------------------------------------
template<bool OUT_BF16, bool HASADD>
__global__ __launch_bounds__(256)
void mfma_nt(const ushort* __restrict__ A, const ushort* __restrict__ B,
             const float* __restrict__ addend, void* __restrict__ Cout,
             int N, int K, float scale)
{
    __shared__ ushort As[128][40];   // pad 32->40: 2-way bank alias only (free)
    __shared__ ushort Bs[128][40];

    const int t = threadIdx.x;
    const int wave = t >> 6, lane = t & 63;
    const int wm = (wave >> 1) * 64, wn = (wave & 1) * 64;
    const int lrow = lane & 15, lko = (lane >> 4) * 8;
    const int m0 = blockIdx.y * 128, n0 = blockIdx.x * 128;

    f32x4 acc[4][4];
    #pragma unroll
    for (int i = 0; i < 4; ++i)
        #pragma unroll
        for (int j = 0; j < 4; ++j) acc[i][j] = (f32x4)0.0f;

    // staging: 4 threads/row, 8 ushorts (16B) each, rows t>>2 and 64+(t>>2)
    const int sr = t >> 2, skc = (t & 3) << 3;
    const ushort* Ap = A + (size_t)(m0 + sr) * K + skc;
    const ushort* Bp = B + (size_t)(n0 + sr) * K + skc;

    uint4 av0 = *(const uint4*)(Ap);
    uint4 av1 = *(const uint4*)(Ap + (size_t)64 * K);
    uint4 bv0 = *(const uint4*)(Bp);
    uint4 bv1 = *(const uint4*)(Bp + (size_t)64 * K);

    for (int k0 = 0; k0 < K; k0 += 32) {
        *(uint4*)&As[sr][skc]      = av0;
        *(uint4*)&As[64 + sr][skc] = av1;
        *(uint4*)&Bs[sr][skc]      = bv0;
        *(uint4*)&Bs[64 + sr][skc] = bv1;
        __syncthreads();

        const bool more = (k0 + 32) < K;
        if (more) {  // prefetch next tile while MFMAs run
            av0 = *(const uint4*)(Ap + k0 + 32);
            av1 = *(const uint4*)(Ap + (size_t)64 * K + k0 + 32);
            bv0 = *(const uint4*)(Bp + k0 + 32);
            bv1 = *(const uint4*)(Bp + (size_t)64 * K + k0 + 32);
        }

        short8 a[4], b[4];
        #pragma unroll
        for (int i = 0; i < 4; ++i)
            a[i] = *(const short8*)&As[wm + i * 16 + lrow][lko];
        #pragma unroll
        for (int j = 0; j < 4; ++j)
            b[j] = *(const short8*)&Bs[wn + j * 16 + lrow][lko];

        #pragma unroll
        for (int i = 0; i < 4; ++i)
            #pragma unroll
            for (int j = 0; j < 4; ++j)
                acc[i][j] = __builtin_amdgcn_mfma_f32_16x16x32_bf16(
                    a[i], b[j], acc[i][j], 0, 0, 0);
        __syncthreads();
    }

    // epilogue: D row = (lane>>4)*4 + reg, col = lane&15  [m89-verified]
    float* Cf = (float*)Cout;
    ushort* Cb = (ushort*)Cout;
    const int quad = lane >> 4;
    #pragma unroll
    for (int i = 0; i < 4; ++i) {
        #pragma unroll
        for (int j = 0; j < 4; ++j) {
            #pragma unroll
            for (int r = 0; r < 4; ++r) {
                const int m = m0 + wm + i * 16 + quad * 4 + r;
                const int n = n0 + wn + j * 16 + lrow;
                float v = acc[i][j][r] * scale;
                const size_t off = (size_t)m * N + n;
                if (HASADD) v += addend[off];
                if (OUT_BF16) Cb[off] = f2bf(v);
                else          Cf[off] = v;
            }
        }
    }
}

// ---------------------------------------------------------------------------
// softmax over rows of 256 fp32 scores -> bf16 attn. One wave per row.
// ---------------------------------------------------------------------------
__global__ __launch_bounds__(256)
void softmax_kernel(const float* __restrict__ S, ushort* __restrict__ Ab)
{
    const int row = blockIdx.x * 4 + (threadIdx.x >> 6);
    const int lane = threadIdx.x & 63;
    const float4 v = *(const float4*)(S + (size_t)row * 256 + lane * 4);

    float m = fmaxf(fmaxf(v.x, v.y), fmaxf(v.z, v.w));
    #pragma unroll
    for (int off = 32; off; off >>= 1) m = fmaxf(m, __shfl_xor(m, off));

    const float e0 = __expf(v.x - m), e1 = __expf(v.y - m);
    const float e2 = __expf(v.z - m), e3 = __expf(v.w - m);
    float s = e0 + e1 + e2 + e3;
    #pragma unroll
    for (int off = 32; off; off >>= 1) s += __shfl_xor(s, off);

    const float inv = 1.0f / s;
    ushort4 o;
    o.x = f2bf(e0 * inv); o.y = f2bf(e1 * inv);
    o.z = f2bf(e2 * inv); o.w = f2bf(e3 * inv);
    *(ushort4*)(Ab + (size_t)row * 256 + lane * 4) = o;
}

extern "C" void kernel_launch(void* const* d_in, const int* in_sizes, int n_in,
                              void* d_out, int out_size, void* d_ws, size_t ws_size,
                              hipStream_t stream)
{
    const float* J     = (const float*)d_in[0];  // [1024,1024]
    const float* conf  = (const float*)d_in[1];  // [256,1024]
    const float* prior = (const float*)d_in[2];  // [256]
    const float* Wq    = (const float*)d_in[3];  // [1024,768]
    const float* Wk    = (const float*)d_in[4];  // [1024,768]
    float* out = (float*)d_out;                  // [1024,1024]

    ushort* ws = (ushort*)d_ws;
    ushort* Jb    = ws;                  // 1024*1024
    ushort* confb = Jb    + 1048576;     // 256*1024
    ushort* WqT   = confb + 262144;      // 768*1024
    ushort* WkT   = WqT   + 786432;      // 768*1024
    ushort* cpT   = WkT   + 786432;      // 1024*256
    ushort* qb    = cpT   + 262144;      // 1024*768
    ushort* kmb   = qb    + 786432;      // 256*768
    ushort* attnb = kmb   + 196608;      // 1024*256
    float*  scores = (float*)(attnb + 262144);  // 1024*256 fp32

    // 1. build bf16 operands
    prep_kernel<<<3072, 256, 0, stream>>>(J, conf, prior, Wq, Wk,
                                          Jb, confb, WqT, WkT, cpT);
    // 2. q = J @ Wq          [1024,768]
    mfma_nt<true, false><<<dim3(6, 8), 256, 0, stream>>>(
        Jb, WqT, nullptr, qb, 768, 1024, 1.0f);
    // 3. km = conf @ Wk      [256,768]
    mfma_nt<true, false><<<dim3(6, 2), 256, 0, stream>>>(
        confb, WkT, nullptr, kmb, 768, 1024, 1.0f);
    // 4. scores = q @ km^T / 32   [1024,256]
    mfma_nt<false, false><<<dim3(2, 8), 256, 0, stream>>>(
        qb, kmb, nullptr, scores, 256, 768, 0.03125f);
    // 5. attn = softmax(scores) -> bf16
    softmax_kernel<<<256, 256, 0, stream>>>(scores, attnb);
    // 6. out = J + attn @ cpT^T   [1024,1024]
    mfma_nt<false, true><<<dim3(8, 8), 256, 0, stream>>>(
        attnb, cpT, J, out, 1024, 256, 1.0f);
}

// Round 4
// 95.800 us; speedup vs baseline: 2.9391x; 1.3672x over previous
//
#include <hip/hip_runtime.h>
#include <hip/hip_bf16.h>

// B=1024, K(conf)=256, D=1024, P=768.
// 4 launches: prep -> (q|km fused) -> scores -> (softmax+out fused).

typedef __attribute__((ext_vector_type(8))) short short8;   // 8 bf16
typedef __attribute__((ext_vector_type(4))) float f32x4;    // MFMA acc

__device__ __forceinline__ ushort f2bf(float x) {
    union { float f; uint u; } c; c.f = x;
    return (ushort)((c.u + 0x7FFFu + ((c.u >> 16) & 1u)) >> 16);  // RNE
}
__device__ __forceinline__ float bflo(uint u) {     // bf16 bits in LOW half
    union { uint u; float f; } c; c.u = u << 16; return c.f;
}
__device__ __forceinline__ float bfhi(uint u) {     // bf16 bits in HIGH half
    union { uint u; float f; } c; c.u = u & 0xFFFF0000u; return c.f;
}

// ---------------------------------------------------------------------------
// prep: build all bf16 NT operands (verified round 2).
// ---------------------------------------------------------------------------
__global__ __launch_bounds__(256)
void prep_kernel(const float* __restrict__ J, const float* __restrict__ conf,
                 const float* __restrict__ prior, const float* __restrict__ Wq,
                 const float* __restrict__ Wk,
                 ushort* __restrict__ Jb, ushort* __restrict__ confb,
                 ushort* __restrict__ WqT, ushort* __restrict__ WkT,
                 ushort* __restrict__ cpT)
{
    const int t = threadIdx.x;
    int b = blockIdx.x;

    if (b < 1280) {  // flat convert J, conf
        const float* src; ushort* dst; int base;
        if (b < 1024) { src = J;    dst = Jb;    base = b * 1024; }
        else          { src = conf; dst = confb; base = (b - 1024) * 1024; }
        const float4 v = *(const float4*)(src + base + t * 4);
        ushort4 o;
        o.x = f2bf(v.x); o.y = f2bf(v.y); o.z = f2bf(v.z); o.w = f2bf(v.w);
        *(ushort4*)(dst + base + t * 4) = o;
        return;
    }

    __shared__ float tile[32][33];
    const float* src; ushort* dst; int R, C, tpr; bool usePrior;
    if (b < 2048)      { b -= 1280; src = Wq;   dst = WqT; R = 1024; C = 768;  tpr = 24; usePrior = false; }
    else if (b < 2816) { b -= 2048; src = Wk;   dst = WkT; R = 1024; C = 768;  tpr = 24; usePrior = false; }
    else               { b -= 2816; src = conf; dst = cpT; R = 256;  C = 1024; tpr = 32; usePrior = true;  }
    const int rt = b / tpr, ct = b % tpr;

    {
        const int row = t >> 3, c4 = (t & 7) << 2;
        const float4 v = *(const float4*)(src + (size_t)(rt * 32 + row) * C + ct * 32 + c4);
        const float p = usePrior ? prior[rt * 32 + row] : 1.0f;
        tile[row][c4 + 0] = v.x * p; tile[row][c4 + 1] = v.y * p;
        tile[row][c4 + 2] = v.z * p; tile[row][c4 + 3] = v.w * p;
    }
    __syncthreads();
    {
        const int orow = t >> 3, oc4 = (t & 7) << 2;
        ushort4 o;
        o.x = f2bf(tile[oc4 + 0][orow]); o.y = f2bf(tile[oc4 + 1][orow]);
        o.z = f2bf(tile[oc4 + 2][orow]); o.w = f2bf(tile[oc4 + 3][orow]);
        *(ushort4*)(dst + (size_t)(ct * 32 + orow) * R + rt * 32 + oc4) = o;
    }
}

// ---------------------------------------------------------------------------
// 64x64 NT GEMM core: C_bf16[64,64] = scale * A[64,K] @ B[64,K]^T
// 256 threads = 4 waves, each 32x32 (2x2 of 16x16x32 MFMA). BK=64.
// ---------------------------------------------------------------------------
struct LdsTiles {
    __align__(16) ushort As[64][72];
    __align__(16) ushort Bs[64][72];
};

__device__ __forceinline__
void gemm64_core(LdsTiles& S, const ushort* __restrict__ A,
                 const ushort* __restrict__ B, ushort* __restrict__ Cb,
                 int m0, int n0, int N, int K, float scale)
{
    const int t = threadIdx.x;
    const int wave = t >> 6, lane = t & 63;
    const int wm = (wave >> 1) * 32, wn = (wave & 1) * 32;
    const int lrow = lane & 15, lko = (lane >> 4) * 8;

    f32x4 acc[2][2];
    #pragma unroll
    for (int i = 0; i < 2; ++i)
        #pragma unroll
        for (int j = 0; j < 2; ++j) acc[i][j] = (f32x4)0.0f;

    const int sr = t >> 2, sk = (t & 3) << 4;   // 64 rows x 64 k, 2 uint4/thread
    const ushort* Ap = A + (size_t)(m0 + sr) * K + sk;
    const ushort* Bp = B + (size_t)(n0 + sr) * K + sk;

    uint4 av0 = *(const uint4*)(Ap);
    uint4 av1 = *(const uint4*)(Ap + 8);
    uint4 bv0 = *(const uint4*)(Bp);
    uint4 bv1 = *(const uint4*)(Bp + 8);

    for (int k0 = 0; k0 < K; k0 += 64) {
        *(uint4*)&S.As[sr][sk]     = av0;
        *(uint4*)&S.As[sr][sk + 8] = av1;
        *(uint4*)&S.Bs[sr][sk]     = bv0;
        *(uint4*)&S.Bs[sr][sk + 8] = bv1;
        __syncthreads();
        if (k0 + 64 < K) {
            av0 = *(const uint4*)(Ap + k0 + 64);
            av1 = *(const uint4*)(Ap + k0 + 72);
            bv0 = *(const uint4*)(Bp + k0 + 64);
            bv1 = *(const uint4*)(Bp + k0 + 72);
        }
        #pragma unroll
        for (int kk = 0; kk < 64; kk += 32) {
            const short8 a0 = *(const short8*)&S.As[wm + lrow][kk + lko];
            const short8 a1 = *(const short8*)&S.As[wm + 16 + lrow][kk + lko];
            const short8 b0 = *(const short8*)&S.Bs[wn + lrow][kk + lko];
            const short8 b1 = *(const short8*)&S.Bs[wn + 16 + lrow][kk + lko];
            acc[0][0] = __builtin_amdgcn_mfma_f32_16x16x32_bf16(a0, b0, acc[0][0], 0, 0, 0);
            acc[0][1] = __builtin_amdgcn_mfma_f32_16x16x32_bf16(a0, b1, acc[0][1], 0, 0, 0);
            acc[1][0] = __builtin_amdgcn_mfma_f32_16x16x32_bf16(a1, b0, acc[1][0], 0, 0, 0);
            acc[1][1] = __builtin_amdgcn_mfma_f32_16x16x32_bf16(a1, b1, acc[1][1], 0, 0, 0);
        }
        __syncthreads();
    }

    const int quad = lane >> 4;  // D: row=(lane>>4)*4+reg, col=lane&15
    #pragma unroll
    for (int i = 0; i < 2; ++i)
        #pragma unroll
        for (int j = 0; j < 2; ++j)
            #pragma unroll
            for (int r = 0; r < 4; ++r) {
                const int m = m0 + wm + i * 16 + quad * 4 + r;
                const int n = n0 + wn + j * 16 + lrow;
                Cb[(size_t)m * N + n] = f2bf(acc[i][j][r] * scale);
            }
}

// q = Jb @ WqT^T (192 blocks) and km = confb @ WkT^T (48 blocks), one dispatch
__global__ __launch_bounds__(256)
void qk_kernel(const ushort* __restrict__ Jb, const ushort* __restrict__ WqT,
               const ushort* __restrict__ confb, const ushort* __restrict__ WkT,
               ushort* __restrict__ qb, ushort* __restrict__ kmb)
{
    __shared__ LdsTiles S;
    int bid = blockIdx.x;
    const ushort *A, *B; ushort* C;
    if (bid < 192) { A = Jb; B = WqT; C = qb; }
    else           { bid -= 192; A = confb; B = WkT; C = kmb; }
    const int mt = bid / 12, nt = bid % 12;
    gemm64_core(S, A, B, C, mt * 64, nt * 64, 768, 1024, 1.0f);
}

// scores(bf16) = (qb @ kmb^T) / 32   [1024,256], 64 blocks
__global__ __launch_bounds__(256)
void scores_kernel(const ushort* __restrict__ qb, const ushort* __restrict__ kmb,
                   ushort* __restrict__ sc)
{
    __shared__ LdsTiles S;
    gemm64_core(S, qb, kmb, sc, blockIdx.y * 64, blockIdx.x * 64, 256, 768, 0.03125f);
}

// ---------------------------------------------------------------------------
// out = J + softmax(scores) @ cpT^T.  Grid (16,16), 64x64 out tile, K=256.
// Prologue: per-row softmax of bf16 scores -> unnormalized exp (bf16) in LDS
// as the A-operand; per-row 1/sum applied in the epilogue (exact norm).
// ---------------------------------------------------------------------------
__global__ __launch_bounds__(256)
void out_kernel(const ushort* __restrict__ sc, const ushort* __restrict__ cpT,
                const float* __restrict__ J, float* __restrict__ out)
{
    __shared__ __align__(16) ushort At[64][264];    // exp(scores) bf16, K=256 + pad
    __shared__ __align__(16) ushort Bs[64][72];
    __shared__ float rowInv[64];

    const int t = threadIdx.x;
    const int m0 = blockIdx.y * 64, n0 = blockIdx.x * 64;

    // ---- softmax prologue: 4 threads per row, 64 cols each
    {
        const int row = t >> 2;
        const int cb  = (t & 3) * 64;          // ushort offset in row
        const ushort* srow = sc + (size_t)(m0 + row) * 256 + cb;
        uint4 s[8];
        #pragma unroll
        for (int i = 0; i < 8; ++i) s[i] = *(const uint4*)(srow + i * 8);

        float mx = -1e30f;
        #pragma unroll
        for (int i = 0; i < 8; ++i) {
            mx = fmaxf(mx, fmaxf(fmaxf(bflo(s[i].x), bfhi(s[i].x)),
                                 fmaxf(bflo(s[i].y), bfhi(s[i].y))));
            mx = fmaxf(mx, fmaxf(fmaxf(bflo(s[i].z), bfhi(s[i].z)),
                                 fmaxf(bflo(s[i].w), bfhi(s[i].w))));
        }
        mx = fmaxf(mx, __shfl_xor(mx, 1));
        mx = fmaxf(mx, __shfl_xor(mx, 2));

        float sum = 0.0f;
        #pragma unroll
        for (int i = 0; i < 8; ++i) {
            uint4 o;
            uint* su = (uint*)&s[i];
            uint* ou = (uint*)&o;
            #pragma unroll
            for (int w = 0; w < 4; ++w) {
                const ushort e0 = f2bf(__expf(bflo(su[w]) - mx));
                const ushort e1 = f2bf(__expf(bfhi(su[w]) - mx));
                // BUGFIX (round 3 -> 4): e0/e1 are raw bf16 bits; bflo()
                // already shifts <<16. The extra "<<16" here zeroed the sum
                // -> rowInv = inf -> absmax = inf.
                sum += bflo((uint)e0) + bflo((uint)e1);
                ou[w] = (uint)e0 | ((uint)e1 << 16);
            }
            *(uint4*)&At[row][cb + i * 8] = o;
        }
        sum += __shfl_xor(sum, 1);
        sum += __shfl_xor(sum, 2);
        if ((t & 3) == 0) rowInv[row] = 1.0f / sum;
    }
    __syncthreads();

    // ---- GEMM: out_tile = expS[64,256] @ cpT_tile[64,256]^T
    const int wave = t >> 6, lane = t & 63;
    const int wm = (wave >> 1) * 32, wn = (wave & 1) * 32;
    const int lrow = lane & 15, lko = (lane >> 4) * 8;

    f32x4 acc[2][2];
    #pragma unroll
    for (int i = 0; i < 2; ++i)
        #pragma unroll
        for (int j = 0; j < 2; ++j) acc[i][j] = (f32x4)0.0f;

    const int sr = t >> 2, sk = (t & 3) << 4;
    const ushort* Bp = cpT + (size_t)(n0 + sr) * 256 + sk;
    uint4 bv0 = *(const uint4*)(Bp);
    uint4 bv1 = *(const uint4*)(Bp + 8);

    for (int k0 = 0; k0 < 256; k0 += 64) {
        *(uint4*)&Bs[sr][sk]     = bv0;
        *(uint4*)&Bs[sr][sk + 8] = bv1;
        __syncthreads();
        if (k0 + 64 < 256) {
            bv0 = *(const uint4*)(Bp + k0 + 64);
            bv1 = *(const uint4*)(Bp + k0 + 72);
        }
        #pragma unroll
        for (int kk = 0; kk < 64; kk += 32) {
            const short8 a0 = *(const short8*)&At[wm + lrow][k0 + kk + lko];
            const short8 a1 = *(const short8*)&At[wm + 16 + lrow][k0 + kk + lko];
            const short8 b0 = *(const short8*)&Bs[wn + lrow][kk + lko];
            const short8 b1 = *(const short8*)&Bs[wn + 16 + lrow][kk + lko];
            acc[0][0] = __builtin_amdgcn_mfma_f32_16x16x32_bf16(a0, b0, acc[0][0], 0, 0, 0);
            acc[0][1] = __builtin_amdgcn_mfma_f32_16x16x32_bf16(a0, b1, acc[0][1], 0, 0, 0);
            acc[1][0] = __builtin_amdgcn_mfma_f32_16x16x32_bf16(a1, b0, acc[1][0], 0, 0, 0);
            acc[1][1] = __builtin_amdgcn_mfma_f32_16x16x32_bf16(a1, b1, acc[1][1], 0, 0, 0);
        }
        __syncthreads();
    }

    const int quad = lane >> 4;
    #pragma unroll
    for (int i = 0; i < 2; ++i)
        #pragma unroll
        for (int j = 0; j < 2; ++j)
            #pragma unroll
            for (int r = 0; r < 4; ++r) {
                const int mrel = wm + i * 16 + quad * 4 + r;
                const int m = m0 + mrel;
                const int n = n0 + wn + j * 16 + lrow;
                const size_t off = (size_t)m * 1024 + n;
                out[off] = acc[i][j][r] * rowInv[mrel] + J[off];
            }
}

extern "C" void kernel_launch(void* const* d_in, const int* in_sizes, int n_in,
                              void* d_out, int out_size, void* d_ws, size_t ws_size,
                              hipStream_t stream)
{
    const float* J     = (const float*)d_in[0];
    const float* conf  = (const float*)d_in[1];
    const float* prior = (const float*)d_in[2];
    const float* Wq    = (const float*)d_in[3];
    const float* Wk    = (const float*)d_in[4];
    float* out = (float*)d_out;

    ushort* ws = (ushort*)d_ws;
    ushort* Jb    = ws;                  // 1024*1024
    ushort* confb = Jb    + 1048576;     // 256*1024
    ushort* WqT   = confb + 262144;      // 768*1024
    ushort* WkT   = WqT   + 786432;      // 768*1024
    ushort* cpT   = WkT   + 786432;      // 1024*256
    ushort* qb    = cpT   + 262144;      // 1024*768
    ushort* kmb   = qb    + 786432;      // 256*768
    ushort* scb   = kmb   + 196608;      // 1024*256 bf16 scores

    prep_kernel<<<3072, 256, 0, stream>>>(J, conf, prior, Wq, Wk,
                                          Jb, confb, WqT, WkT, cpT);
    qk_kernel<<<240, 256, 0, stream>>>(Jb, WqT, confb, WkT, qb, kmb);
    scores_kernel<<<dim3(4, 16), 256, 0, stream>>>(qb, kmb, scb);
    out_kernel<<<dim3(16, 16), 256, 0, stream>>>(scb, cpT, J, out);
}